// Round 14
// baseline (29.668 us; speedup 1.0000x reference)
//
#include <hip/hip_runtime.h>
#include <math.h>

#define S 96
#define SM 95
#define WPB 16           // waves per march block; 2 rays/wave -> 32 rays/block
#define L2E 1.4426950408889634f

typedef float vf3 __attribute__((ext_vector_type(3)));

__device__ __forceinline__ float fexp2(float x) {
#if __has_builtin(__builtin_amdgcn_exp2f)
    return __builtin_amdgcn_exp2f(x);   // v_exp_f32: 2^x
#else
    return exp2f(x);
#endif
}
__device__ __forceinline__ float flog2(float x) {
#if __has_builtin(__builtin_amdgcn_logf)
    return __builtin_amdgcn_logf(x);    // v_log_f32: log2(x)
#else
    return log2f(x);
#endif
}

// DPP helper: invalid/masked lanes receive `old`.
template <int CTRL, int RMASK>
__device__ __forceinline__ float updpp(float old, float src) {
    return __int_as_float(__builtin_amdgcn_update_dpp(
        __float_as_int(old), __float_as_int(src), CTRL, RMASK, 0xF, false));
}
template <int CTRL, int RMASK>
__device__ __forceinline__ float updpp0(float src) {
    return __int_as_float(__builtin_amdgcn_update_dpp(
        0, __float_as_int(src), CTRL, RMASK, 0xF, false));
}

// 32-lane inclusive prefix-sum within each wave half (5 DPP, all VALU).
// After: lane 31 holds sum of lanes 0..31, lane 63 holds sum of 32..63.
__device__ __forceinline__ float scan32(float x) {
    x += updpp0<0x111, 0xF>(x);  // row_shr:1
    x += updpp0<0x112, 0xF>(x);  // row_shr:2
    x += updpp0<0x114, 0xF>(x);  // row_shr:4
    x += updpp0<0x118, 0xF>(x);  // row_shr:8
    x += updpp0<0x142, 0xA>(x);  // row_bcast:15 -> rows 1,3 (stays in half)
    return x;
}
// 32-lane min/max ladders (identity-preserving via `old`)
__device__ __forceinline__ float redmin32(float x) {
    x = fminf(x, updpp<0x111, 0xF>(INFINITY, x));
    x = fminf(x, updpp<0x112, 0xF>(INFINITY, x));
    x = fminf(x, updpp<0x114, 0xF>(INFINITY, x));
    x = fminf(x, updpp<0x118, 0xF>(INFINITY, x));
    x = fminf(x, updpp<0x142, 0xA>(INFINITY, x));
    return x;                    // lane 31 = min of lanes 0..31
}
__device__ __forceinline__ float redmax32(float x) {
    x = fmaxf(x, updpp<0x111, 0xF>(-INFINITY, x));
    x = fmaxf(x, updpp<0x112, 0xF>(-INFINITY, x));
    x = fmaxf(x, updpp<0x114, 0xF>(-INFINITY, x));
    x = fmaxf(x, updpp<0x118, 0xF>(-INFINITY, x));
    x = fmaxf(x, updpp<0x143, 0xC>(-INFINITY, x));  // row_bcast:31 -> row 2,3
    return x;                    // lane 63 = max of lanes 32..63
}

__device__ __forceinline__ float rdlane(float x, int lane) {
    return __int_as_float(__builtin_amdgcn_readlane(__float_as_int(x), lane));
}
// wave-wide lane shifts (VALU): shr1: lane l <- l-1; shl1: lane l <- l+1
__device__ __forceinline__ float wshr1(float x) { return updpp0<0x138, 0xF>(x); }
__device__ __forceinline__ float wshl1(float x) { return updpp0<0x130, 0xF>(x); }

// atomic-fallback init (only if ws too small for slots)
__global__ void init_ws_kernel(unsigned int* ws) {
    ws[0] = 0x7F800000u;  // +inf
    ws[1] = 0xFF800000u;  // -inf
}

// ---------------------------------------------------------------------------
// TWO rays per wave: lanes 0-31 = ray 2w, lanes 32-63 = ray 2w+1.
// Lane lp (0..31) owns samples 3lp..3lp+2 and midpoints 3lp..3lp+2
// (midpoint 95 at lp=31 masked). Log-space transmittance:
//   dd_i = (d_{i+1}-d_i)*log2(1+exp((s_i+s_{i+1})/2));  T_j = exp2(-prefix)
//   w_i = T_i - T_{i+1};  rgb/dep via v_j = 0.5*(T_{j-1}-T_{j+1});
//   1-wtot = T_95 (telescoping).
// No LDS, no __syncthreads: wave 0 alone gathers the block's 32 ray depth
// bounds (d[r][0] lanes 0-31, d[r][95] lanes 32-63) and writes the slot.
// out_w stores are NONTEMPORAL (streaming, no L2 pollution).
// Depth stored raw (NaN->inf); tail_kernel clamps with global min/max.
// ---------------------------------------------------------------------------
template <bool SLOT>
__global__ __launch_bounds__(WPB * 64) void march_kernel(
    const float* __restrict__ colors,
    const float* __restrict__ dens,
    const float* __restrict__ depths,
    const int* __restrict__ white_back,
    unsigned int* __restrict__ ws,
    float* __restrict__ out_rgb,   // [nrays,3]
    float* __restrict__ out_dep,   // [nrays] raw
    float* __restrict__ out_w,     // [nrays,95]
    int nrays, int nblocks) {
    const int wv = threadIdx.x >> 6;
    const int l = threadIdx.x & 63;
    const int lp = l & 31;
    const int ray0 = (blockIdx.x * WPB + wv) * 2 + (l >> 5);
    const bool valid = (ray0 < nrays);
    const int ray = valid ? ray0 : (nrays - 1);
    const int wb = *white_back;

    // ---- wave 0 only: block depth bounds (no barrier, no LDS)
    if (wv == 0) {
        int r = blockIdx.x * (2 * WPB) + lp;
        if (r >= nrays) r = nrays - 1;
        float v = depths[r * S + ((l < 32) ? 0 : SM)];
        float mn = redmin32((l < 32) ? v : INFINITY);     // lane 31
        float mx = redmax32((l < 32) ? INFINITY : v);     // lane 63
        float bmn = rdlane(mn, 31);
        float bmx = rdlane(mx, 63);
        if (l == 0) {
            if (SLOT) {
                float* sl = (float*)ws;
                sl[blockIdx.x] = bmn;
                sl[nblocks + blockIdx.x] = bmx;
            } else {
                atomicMin((int*)&ws[0], __float_as_int(bmn));
                atomicMax((int*)&ws[1], __float_as_int(bmx));
            }
        }
    }

    const int doff = ray * S + 3 * lp;          // 32-bit offsets throughout
    const int coff = ray * (3 * S) + 9 * lp;

    const float3 dv = *(const float3*)(depths + doff);
    const float3 sv = *(const float3*)(dens + doff);
    const float3 ca = *(const float3*)(colors + coff);      // color sample 3lp
    const float3 cb = *(const float3*)(colors + coff + 3);  // 3lp+1
    const float3 cc = *(const float3*)(colors + coff + 6);  // 3lp+2

    // ---- neighbor sample 3lp+3 (lane+1's first); 32-boundary leak lands
    // only in masked midpoint 95 -> no patch needed
    float dn = wshl1(dv.x);
    float sn = wshl1(sv.x);

    // ---- softplus (log2 space) per owned midpoint
    const float C1 = 0.5f * L2E;
    float x0 = (sv.x + sv.y) * C1;
    float x1 = (sv.y + sv.z) * C1;
    float x2 = (sv.z + sn) * C1;
    float sp0 = fmaxf(x0, 0.f) + flog2(1.f + fexp2(-fabsf(x0)));
    float sp1 = fmaxf(x1, 0.f) + flog2(1.f + fexp2(-fabsf(x1)));
    float sp2 = fmaxf(x2, 0.f) + flog2(1.f + fexp2(-fabsf(x2)));
    float dd0 = (dv.y - dv.x) * sp0;
    float dd1 = (dv.z - dv.y) * sp1;
    float dd2 = (lp < 31) ? (dn - dv.z) * sp2 : 0.f;   // midpoint 95 masked

    // ---- local cumsum + 32-lane scan
    float cum1 = dd0 + dd1;
    float cum2 = cum1 + dd2;
    float incl = scan32(cum2);
    float base = incl - cum2;        // exclusive prefix (sum of prior lanes)

    float T0 = fexp2(-base);          // T at sample 3lp
    float T1 = fexp2(-(base + dd0));  // 3lp+1
    float T2 = fexp2(-(base + cum1)); // 3lp+2
    float T3 = fexp2(-incl);          // 3lp+3 (lp=31: T_96 := T_95)

    float w0 = T0 - T1;              // weight midpoint 3lp
    float w1 = T1 - T2;              // 3lp+1
    float w2 = T2 - T3;              // 3lp+2 (invalid at lp=31)

    // ---- per-sample coefficients v_j (0.5 deferred to output)
    float Tm1 = wshr1(T2);           // prev lane's T(3lp-1)
    if (lp == 0) Tm1 = 1.f;          // T_{-1} := T_0 = 1
    float v0 = Tm1 - T1;
    float v1 = T0 - T2;
    float v2 = T1 - T3;

    // ---- weighted accumulation + 32-lane reductions (totals at lanes 31/63)
    float racc = v0 * ca.x + v1 * cb.x + v2 * cc.x;
    float gacc = v0 * ca.y + v1 * cb.y + v2 * cc.y;
    float bacc = v0 * ca.z + v1 * cb.z + v2 * cc.z;
    float dacc = v0 * dv.x + v1 * dv.y + v2 * dv.z;
    racc = scan32(racc);
    gacc = scan32(gacc);
    bacc = scan32(bacc);
    dacc = scan32(dacc);

    if (!valid) return;   // no barriers below; only stores

    const int woff = ray * SM + 3 * lp;
    if (lp < 31) {
        vf3 wv3 = {w0, w1, w2};
        __builtin_nontemporal_store(wv3, (vf3*)(out_w + woff));  // dwordx3 nt
    } else {
        __builtin_nontemporal_store(w0, out_w + woff);     // midpoints 93, 94
        __builtin_nontemporal_store(w1, out_w + woff + 1);
    }

    if (lp == 31) {                  // lane 31 -> ray A, lane 63 -> ray B
        float T95 = T2;              // T at sample 95 (local at lp=31)
        float rr = 0.5f * racc, gg = 0.5f * gacc, bb = 0.5f * bacc;
        if (wb) { rr += T95; gg += T95; bb += T95; }  // 1-wtot = T_95
        out_rgb[ray * 3 + 0] = rr;
        out_rgb[ray * 3 + 1] = gg;
        out_rgb[ray * 3 + 2] = bb;
        float cd = 0.5f * dacc;
        if (isnan(cd)) cd = INFINITY;  // nan_to_num(nan=inf)
        out_dep[ray] = cd;             // clamped by tail_kernel
    }
}

// Merged finalize+clamp: every block redundantly reduces the slot arrays
// (float4, L2-resident, 2 iters/thread at nblocks=2048) then clamps its
// contiguous chunk of out_dep.
__global__ __launch_bounds__(256) void tail_kernel(
    float* __restrict__ dep, const unsigned int* __restrict__ ws,
    int n, int nblocks, int slotMode) {
    float gmn, gmx;
    if (slotMode) {
        const float* sl = (const float*)ws;
        float mn = INFINITY, mx = -INFINITY;
        const int nv = nblocks >> 2;                    // float4 count
        const float4* mn4 = (const float4*)sl;
        const float4* mx4 = (const float4*)(sl + nblocks);
        for (int i = threadIdx.x; i < nv; i += 256) {
            float4 a = mn4[i];
            float4 b = mx4[i];
            mn = fminf(mn, fminf(fminf(a.x, a.y), fminf(a.z, a.w)));
            mx = fmaxf(mx, fmaxf(fmaxf(b.x, b.y), fmaxf(b.z, b.w)));
        }
        for (int i = (nv << 2) + threadIdx.x; i < nblocks; i += 256) {
            mn = fminf(mn, sl[i]);
            mx = fmaxf(mx, sl[nblocks + i]);
        }
#pragma unroll
        for (int off = 32; off >= 1; off >>= 1) {
            mn = fminf(mn, __shfl_xor(mn, off));
            mx = fmaxf(mx, __shfl_xor(mx, off));
        }
        __shared__ float a[4], b[4];
        const int wv = threadIdx.x >> 6;
        if ((threadIdx.x & 63) == 0) { a[wv] = mn; b[wv] = mx; }
        __syncthreads();
        gmn = fminf(fminf(a[0], a[1]), fminf(a[2], a[3]));
        gmx = fmaxf(fmaxf(b[0], b[1]), fmaxf(b[2], b[3]));
    } else {
        gmn = __int_as_float((int)ws[0]);
        gmx = __int_as_float((int)ws[1]);
    }
    int i = blockIdx.x * 256 + threadIdx.x;
    if (i < n) dep[i] = fminf(fmaxf(dep[i], gmn), gmx);
}

extern "C" void kernel_launch(void* const* d_in, const int* in_sizes, int n_in,
                              void* d_out, int out_size, void* d_ws, size_t ws_size,
                              hipStream_t stream) {
    const float* colors = (const float*)d_in[0];
    const float* dens = (const float*)d_in[1];
    const float* depths = (const float*)d_in[2];
    const int* white_back = (const int*)d_in[3];

    const int nrays = in_sizes[1] / S;  // densities: nrays * S
    unsigned int* ws = (unsigned int*)d_ws;

    float* out_rgb = (float*)d_out;                // nrays*3
    float* out_dep = out_rgb + (size_t)nrays * 3;  // nrays
    float* out_w = out_dep + nrays;                // nrays*95

    const int raysPB = 2 * WPB;                    // 32 rays per block
    const int nblocks = (nrays + raysPB - 1) / raysPB;
    const bool slot = ws_size >= (size_t)(2 * nblocks) * sizeof(float);

    if (slot) {
        march_kernel<true><<<nblocks, WPB * 64, 0, stream>>>(
            colors, dens, depths, white_back, ws, out_rgb, out_dep, out_w,
            nrays, nblocks);
    } else {
        init_ws_kernel<<<1, 1, 0, stream>>>(ws);
        march_kernel<false><<<nblocks, WPB * 64, 0, stream>>>(
            colors, dens, depths, white_back, ws, out_rgb, out_dep, out_w,
            nrays, nblocks);
    }
    tail_kernel<<<(nrays + 255) / 256, 256, 0, stream>>>(
        out_dep, ws, nrays, nblocks, slot ? 1 : 0);
}

// Round 15
// 29.063 us; speedup vs baseline: 1.0208x; 1.0208x over previous
//
#include <hip/hip_runtime.h>
#include <math.h>

#define S 96
#define SM 95
#define WPB 16           // waves per march block; 2 rays/wave -> 32 rays/block
#define L2E 1.4426950408889634f

__device__ __forceinline__ float fexp2(float x) {
#if __has_builtin(__builtin_amdgcn_exp2f)
    return __builtin_amdgcn_exp2f(x);   // v_exp_f32: 2^x
#else
    return exp2f(x);
#endif
}
__device__ __forceinline__ float flog2(float x) {
#if __has_builtin(__builtin_amdgcn_logf)
    return __builtin_amdgcn_logf(x);    // v_log_f32: log2(x)
#else
    return log2f(x);
#endif
}

// DPP helper: invalid/masked lanes receive `old`.
template <int CTRL, int RMASK>
__device__ __forceinline__ float updpp(float old, float src) {
    return __int_as_float(__builtin_amdgcn_update_dpp(
        __float_as_int(old), __float_as_int(src), CTRL, RMASK, 0xF, false));
}
template <int CTRL, int RMASK>
__device__ __forceinline__ float updpp0(float src) {
    return __int_as_float(__builtin_amdgcn_update_dpp(
        0, __float_as_int(src), CTRL, RMASK, 0xF, false));
}

// 32-lane inclusive prefix-sum within each wave half (5 DPP, all VALU).
// After: lane 31 holds sum of lanes 0..31, lane 63 holds sum of 32..63.
__device__ __forceinline__ float scan32(float x) {
    x += updpp0<0x111, 0xF>(x);  // row_shr:1
    x += updpp0<0x112, 0xF>(x);  // row_shr:2
    x += updpp0<0x114, 0xF>(x);  // row_shr:4
    x += updpp0<0x118, 0xF>(x);  // row_shr:8
    x += updpp0<0x142, 0xA>(x);  // row_bcast:15 -> rows 1,3 (stays in half)
    return x;
}
// 32-lane min/max ladders (identity-preserving via `old`)
__device__ __forceinline__ float redmin32(float x) {
    x = fminf(x, updpp<0x111, 0xF>(INFINITY, x));
    x = fminf(x, updpp<0x112, 0xF>(INFINITY, x));
    x = fminf(x, updpp<0x114, 0xF>(INFINITY, x));
    x = fminf(x, updpp<0x118, 0xF>(INFINITY, x));
    x = fminf(x, updpp<0x142, 0xA>(INFINITY, x));
    return x;                    // lane 31 = min of lanes 0..31
}
__device__ __forceinline__ float redmax32(float x) {
    x = fmaxf(x, updpp<0x111, 0xF>(-INFINITY, x));
    x = fmaxf(x, updpp<0x112, 0xF>(-INFINITY, x));
    x = fmaxf(x, updpp<0x114, 0xF>(-INFINITY, x));
    x = fmaxf(x, updpp<0x118, 0xF>(-INFINITY, x));
    x = fmaxf(x, updpp<0x143, 0xC>(-INFINITY, x));  // row_bcast:31 -> row 2,3
    return x;                    // lane 63 = max of lanes 32..63
}

__device__ __forceinline__ float rdlane(float x, int lane) {
    return __int_as_float(__builtin_amdgcn_readlane(__float_as_int(x), lane));
}
// wave-wide lane shifts (VALU): shr1: lane l <- l-1; shl1: lane l <- l+1
__device__ __forceinline__ float wshr1(float x) { return updpp0<0x138, 0xF>(x); }
__device__ __forceinline__ float wshl1(float x) { return updpp0<0x130, 0xF>(x); }

// atomic-fallback init (only if ws too small for slots)
__global__ void init_ws_kernel(unsigned int* ws) {
    ws[0] = 0x7F800000u;  // +inf
    ws[1] = 0xFF800000u;  // -inf
}

// ---------------------------------------------------------------------------
// TWO rays per wave: lanes 0-31 = ray 2w, lanes 32-63 = ray 2w+1.
// Lane lp (0..31) owns samples 3lp..3lp+2 and midpoints 3lp..3lp+2
// (midpoint 95 at lp=31 masked). Log-space transmittance:
//   dd_i = (d_{i+1}-d_i)*log2(1+exp((s_i+s_{i+1})/2));  T_j = exp2(-prefix)
//   w_i = T_i - T_{i+1};  rgb/dep via v_j = 0.5*(T_{j-1}-T_{j+1});
//   1-wtot = T_95 (telescoping).
// No LDS, no __syncthreads: wave 0 alone gathers the block's 32 ray depth
// bounds (d[r][0] lanes 0-31, d[r][95] lanes 32-63) and writes the slot.
// Depth stored raw (NaN->inf); tail_kernel clamps with global min/max.
// ---------------------------------------------------------------------------
template <bool SLOT>
__global__ __launch_bounds__(WPB * 64) void march_kernel(
    const float* __restrict__ colors,
    const float* __restrict__ dens,
    const float* __restrict__ depths,
    const int* __restrict__ white_back,
    unsigned int* __restrict__ ws,
    float* __restrict__ out_rgb,   // [nrays,3]
    float* __restrict__ out_dep,   // [nrays] raw
    float* __restrict__ out_w,     // [nrays,95]
    int nrays, int nblocks) {
    const int wv = threadIdx.x >> 6;
    const int l = threadIdx.x & 63;
    const int lp = l & 31;
    const int ray0 = (blockIdx.x * WPB + wv) * 2 + (l >> 5);
    const bool valid = (ray0 < nrays);
    const int ray = valid ? ray0 : (nrays - 1);
    const int wb = *white_back;

    // ---- wave 0 only: block depth bounds (no barrier, no LDS)
    if (wv == 0) {
        int r = blockIdx.x * (2 * WPB) + lp;
        if (r >= nrays) r = nrays - 1;
        float v = depths[r * S + ((l < 32) ? 0 : SM)];
        float mn = redmin32((l < 32) ? v : INFINITY);     // lane 31
        float mx = redmax32((l < 32) ? INFINITY : v);     // lane 63
        float bmn = rdlane(mn, 31);
        float bmx = rdlane(mx, 63);
        if (l == 0) {
            if (SLOT) {
                float* sl = (float*)ws;
                sl[blockIdx.x] = bmn;
                sl[nblocks + blockIdx.x] = bmx;
            } else {
                atomicMin((int*)&ws[0], __float_as_int(bmn));
                atomicMax((int*)&ws[1], __float_as_int(bmx));
            }
        }
    }

    const int doff = ray * S + 3 * lp;          // 32-bit offsets throughout
    const int coff = ray * (3 * S) + 9 * lp;

    const float3 dv = *(const float3*)(depths + doff);
    const float3 sv = *(const float3*)(dens + doff);
    const float3 ca = *(const float3*)(colors + coff);      // color sample 3lp
    const float3 cb = *(const float3*)(colors + coff + 3);  // 3lp+1
    const float3 cc = *(const float3*)(colors + coff + 6);  // 3lp+2

    // ---- neighbor sample 3lp+3 (lane+1's first); 32-boundary leak lands
    // only in masked midpoint 95 -> no patch needed
    float dn = wshl1(dv.x);
    float sn = wshl1(sv.x);

    // ---- softplus (log2 space) per owned midpoint
    const float C1 = 0.5f * L2E;
    float x0 = (sv.x + sv.y) * C1;
    float x1 = (sv.y + sv.z) * C1;
    float x2 = (sv.z + sn) * C1;
    float sp0 = fmaxf(x0, 0.f) + flog2(1.f + fexp2(-fabsf(x0)));
    float sp1 = fmaxf(x1, 0.f) + flog2(1.f + fexp2(-fabsf(x1)));
    float sp2 = fmaxf(x2, 0.f) + flog2(1.f + fexp2(-fabsf(x2)));
    float dd0 = (dv.y - dv.x) * sp0;
    float dd1 = (dv.z - dv.y) * sp1;
    float dd2 = (lp < 31) ? (dn - dv.z) * sp2 : 0.f;   // midpoint 95 masked

    // ---- local cumsum + 32-lane scan
    float cum1 = dd0 + dd1;
    float cum2 = cum1 + dd2;
    float incl = scan32(cum2);
    float base = incl - cum2;        // exclusive prefix (sum of prior lanes)

    float T0 = fexp2(-base);          // T at sample 3lp
    float T1 = fexp2(-(base + dd0));  // 3lp+1
    float T2 = fexp2(-(base + cum1)); // 3lp+2
    float T3 = fexp2(-incl);          // 3lp+3 (lp=31: T_96 := T_95)

    float w0 = T0 - T1;              // weight midpoint 3lp
    float w1 = T1 - T2;              // 3lp+1
    float w2 = T2 - T3;              // 3lp+2 (invalid at lp=31)

    // ---- per-sample coefficients v_j (0.5 deferred to output)
    float Tm1 = wshr1(T2);           // prev lane's T(3lp-1)
    if (lp == 0) Tm1 = 1.f;          // T_{-1} := T_0 = 1
    float v0 = Tm1 - T1;
    float v1 = T0 - T2;
    float v2 = T1 - T3;

    // ---- weighted accumulation + 32-lane reductions (totals at lanes 31/63)
    float racc = v0 * ca.x + v1 * cb.x + v2 * cc.x;
    float gacc = v0 * ca.y + v1 * cb.y + v2 * cc.y;
    float bacc = v0 * ca.z + v1 * cb.z + v2 * cc.z;
    float dacc = v0 * dv.x + v1 * dv.y + v2 * dv.z;
    racc = scan32(racc);
    gacc = scan32(gacc);
    bacc = scan32(bacc);
    dacc = scan32(dacc);

    if (!valid) return;   // no barriers below; only stores

    const int woff = ray * SM + 3 * lp;
    if (lp < 31) {
        float3 wv3 = {w0, w1, w2};
        *(float3*)(out_w + woff) = wv3;          // dwordx3 store
    } else {
        out_w[woff] = w0;                         // midpoints 93, 94
        out_w[woff + 1] = w1;
    }

    if (lp == 31) {                  // lane 31 -> ray A, lane 63 -> ray B
        float T95 = T2;              // T at sample 95 (local at lp=31)
        float rr = 0.5f * racc, gg = 0.5f * gacc, bb = 0.5f * bacc;
        if (wb) { rr += T95; gg += T95; bb += T95; }  // 1-wtot = T_95
        out_rgb[ray * 3 + 0] = rr;
        out_rgb[ray * 3 + 1] = gg;
        out_rgb[ray * 3 + 2] = bb;
        float cd = 0.5f * dacc;
        if (isnan(cd)) cd = INFINITY;  // nan_to_num(nan=inf)
        out_dep[ray] = cd;             // clamped by tail_kernel
    }
}

// Merged finalize+clamp: every block redundantly reduces the slot arrays
// (float4, L2-resident, 2 iters/thread at nblocks=2048) then clamps its
// contiguous chunk of out_dep.
__global__ __launch_bounds__(256) void tail_kernel(
    float* __restrict__ dep, const unsigned int* __restrict__ ws,
    int n, int nblocks, int slotMode) {
    float gmn, gmx;
    if (slotMode) {
        const float* sl = (const float*)ws;
        float mn = INFINITY, mx = -INFINITY;
        const int nv = nblocks >> 2;                    // float4 count
        const float4* mn4 = (const float4*)sl;
        const float4* mx4 = (const float4*)(sl + nblocks);
        for (int i = threadIdx.x; i < nv; i += 256) {
            float4 a = mn4[i];
            float4 b = mx4[i];
            mn = fminf(mn, fminf(fminf(a.x, a.y), fminf(a.z, a.w)));
            mx = fmaxf(mx, fmaxf(fmaxf(b.x, b.y), fmaxf(b.z, b.w)));
        }
        for (int i = (nv << 2) + threadIdx.x; i < nblocks; i += 256) {
            mn = fminf(mn, sl[i]);
            mx = fmaxf(mx, sl[nblocks + i]);
        }
#pragma unroll
        for (int off = 32; off >= 1; off >>= 1) {
            mn = fminf(mn, __shfl_xor(mn, off));
            mx = fmaxf(mx, __shfl_xor(mx, off));
        }
        __shared__ float a[4], b[4];
        const int wv = threadIdx.x >> 6;
        if ((threadIdx.x & 63) == 0) { a[wv] = mn; b[wv] = mx; }
        __syncthreads();
        gmn = fminf(fminf(a[0], a[1]), fminf(a[2], a[3]));
        gmx = fmaxf(fmaxf(b[0], b[1]), fmaxf(b[2], b[3]));
    } else {
        gmn = __int_as_float((int)ws[0]);
        gmx = __int_as_float((int)ws[1]);
    }
    int i = blockIdx.x * 256 + threadIdx.x;
    if (i < n) dep[i] = fminf(fmaxf(dep[i], gmn), gmx);
}

extern "C" void kernel_launch(void* const* d_in, const int* in_sizes, int n_in,
                              void* d_out, int out_size, void* d_ws, size_t ws_size,
                              hipStream_t stream) {
    const float* colors = (const float*)d_in[0];
    const float* dens = (const float*)d_in[1];
    const float* depths = (const float*)d_in[2];
    const int* white_back = (const int*)d_in[3];

    const int nrays = in_sizes[1] / S;  // densities: nrays * S
    unsigned int* ws = (unsigned int*)d_ws;

    float* out_rgb = (float*)d_out;                // nrays*3
    float* out_dep = out_rgb + (size_t)nrays * 3;  // nrays
    float* out_w = out_dep + nrays;                // nrays*95

    const int raysPB = 2 * WPB;                    // 32 rays per block
    const int nblocks = (nrays + raysPB - 1) / raysPB;
    const bool slot = ws_size >= (size_t)(2 * nblocks) * sizeof(float);

    if (slot) {
        march_kernel<true><<<nblocks, WPB * 64, 0, stream>>>(
            colors, dens, depths, white_back, ws, out_rgb, out_dep, out_w,
            nrays, nblocks);
    } else {
        init_ws_kernel<<<1, 1, 0, stream>>>(ws);
        march_kernel<false><<<nblocks, WPB * 64, 0, stream>>>(
            colors, dens, depths, white_back, ws, out_rgb, out_dep, out_w,
            nrays, nblocks);
    }
    tail_kernel<<<(nrays + 255) / 256, 256, 0, stream>>>(
        out_dep, ws, nrays, nblocks, slot ? 1 : 0);
}